// Round 1
// baseline (2599.953 us; speedup 1.0000x reference)
//
#include <hip/hip_runtime.h>

// Problem constants
#define HH   64
#define WW   64
#define CC   8
#define HWC  (HH * WW * CC)   // 32768 floats per sample
#define NPIX (HH * WW)        // 4096
#define GG   512
#define MM   512

// One block per output row b in [0, 2048).
//   e = b >> 9 (expert), sample = indices[b]
// Computes: pooled[0:8]  = mean_hw relu(conv1x1(x, W1))
//           pooled[8:16] = mean_hw relu(conv3x3(x, W3))
//           pooled      += (mean_hw x) @ Wskip          (linearity of 1x1 conv + mean)
//           out[b, :]    = (pooled @ Wd[e]) * cell_mask[e]
__global__ __launch_bounds__(256, 3)
void conv_moe_kernel(const float* __restrict__ x,
                     const int*   __restrict__ idx,
                     const float* __restrict__ W1,
                     const float* __restrict__ W3,
                     const float* __restrict__ Wsk,
                     const float* __restrict__ Wd,
                     const float* __restrict__ cmask,
                     float*       __restrict__ out)
{
    __shared__ float w3s[9][8][8];   // [tap][cin][cout]
    __shared__ float w1s[8][8];      // [cin][cout]
    __shared__ float red[4][24];
    __shared__ float rsum[24];
    __shared__ float pooledS[16];

    const int b   = blockIdx.x;
    const int e   = b >> 9;
    const int tid = threadIdx.x;
    const int samp = idx[b];

    // stage expert weights into LDS
    for (int i = tid; i < 576; i += 256) ((float*)w3s)[i] = W3[e * 576 + i];
    if (tid < 64) ((float*)w1s)[tid] = W1[e * 64 + tid];
    __syncthreads();

    const float* xb = x + (size_t)samp * HWC;

    float s1[8], s3[8], sx[8];
    #pragma unroll
    for (int i = 0; i < 8; ++i) { s1[i] = 0.f; s3[i] = 0.f; sx[i] = 0.f; }

    // 4096 pixels, 4 consecutive pixels per thread per iteration, 4 iterations
    #pragma unroll 1
    for (int iter = 0; iter < 4; ++iter) {
        const int g    = iter * 256 + tid;   // 4-pixel group id
        const int p0   = g << 2;
        const int row  = p0 >> 6;            // groups never cross rows (64 px/row)
        const int col0 = p0 & 63;

        float t1[4][8], t3[4][8];
        #pragma unroll
        for (int p = 0; p < 4; ++p)
            #pragma unroll
            for (int c = 0; c < 8; ++c) { t1[p][c] = 0.f; t3[p][c] = 0.f; }

        #pragma unroll 1
        for (int dr = 0; dr < 3; ++dr) {
            const int r = row + dr - 1;
            const bool rok = (r >= 0) && (r < HH);

            // input window: cols col0-1 .. col0+4, 8 channels each
            float xr[6][8];
            #pragma unroll
            for (int j = 0; j < 6; ++j) {
                const int c = col0 - 1 + j;
                const bool ok = rok && (c >= 0) && (c < WW);
                float4 a, bb;
                if (ok) {
                    const float4* p4 = (const float4*)(xb + (((r << 6) + c) << 3));
                    a  = p4[0];
                    bb = p4[1];
                } else {
                    a  = make_float4(0.f, 0.f, 0.f, 0.f);
                    bb = make_float4(0.f, 0.f, 0.f, 0.f);
                }
                xr[j][0] = a.x;  xr[j][1] = a.y;  xr[j][2] = a.z;  xr[j][3] = a.w;
                xr[j][4] = bb.x; xr[j][5] = bb.y; xr[j][6] = bb.z; xr[j][7] = bb.w;
            }

            // 3x3 conv taps of this row
            #pragma unroll
            for (int dc = 0; dc < 3; ++dc) {
                const int wt = dr * 3 + dc;
                #pragma unroll
                for (int ci = 0; ci < 8; ++ci) {
                    const float4 wa = *(const float4*)&w3s[wt][ci][0];
                    const float4 wb = *(const float4*)&w3s[wt][ci][4];
                    const float wv[8] = {wa.x, wa.y, wa.z, wa.w, wb.x, wb.y, wb.z, wb.w};
                    #pragma unroll
                    for (int p = 0; p < 4; ++p) {
                        const float xv = xr[dc + p][ci];
                        #pragma unroll
                        for (int co = 0; co < 8; ++co) t3[p][co] += xv * wv[co];
                    }
                }
            }

            // center row: 1x1 conv branch + raw-input sum (for the skip term)
            if (dr == 1) {
                #pragma unroll
                for (int ci = 0; ci < 8; ++ci) {
                    const float4 wa = *(const float4*)&w1s[ci][0];
                    const float4 wb = *(const float4*)&w1s[ci][4];
                    const float wv[8] = {wa.x, wa.y, wa.z, wa.w, wb.x, wb.y, wb.z, wb.w};
                    #pragma unroll
                    for (int p = 0; p < 4; ++p) {
                        const float xv = xr[1 + p][ci];
                        sx[ci] += xv;
                        #pragma unroll
                        for (int co = 0; co < 8; ++co) t1[p][co] += xv * wv[co];
                    }
                }
            }
        }

        // relu + accumulate spatial sums
        #pragma unroll
        for (int p = 0; p < 4; ++p)
            #pragma unroll
            for (int c = 0; c < 8; ++c) {
                s3[c] += fmaxf(t3[p][c], 0.f);
                s1[c] += fmaxf(t1[p][c], 0.f);
            }
    }

    // wave reduction (64 lanes)
    #pragma unroll
    for (int i = 0; i < 8; ++i) {
        #pragma unroll
        for (int off = 32; off > 0; off >>= 1) {
            s1[i] += __shfl_down(s1[i], off);
            s3[i] += __shfl_down(s3[i], off);
            sx[i] += __shfl_down(sx[i], off);
        }
    }
    const int lane = tid & 63;
    const int wid  = tid >> 6;
    if (lane == 0) {
        #pragma unroll
        for (int i = 0; i < 8; ++i) {
            red[wid][i]      = s1[i];
            red[wid][8 + i]  = s3[i];
            red[wid][16 + i] = sx[i];
        }
    }
    __syncthreads();
    if (tid < 24) {
        const float t = red[0][tid] + red[1][tid] + red[2][tid] + red[3][tid];
        rsum[tid] = t * (1.0f / 4096.0f);
    }
    __syncthreads();

    // pooled[k] = branch mean + (mean x) @ Wskip
    if (tid < 16) {
        float acc = rsum[tid];  // k<8: conv1 branch; k>=8: conv3 branch
        #pragma unroll
        for (int ci = 0; ci < 8; ++ci)
            acc += rsum[16 + ci] * Wsk[e * 128 + ci * 16 + tid];
        pooledS[tid] = acc;
    }
    __syncthreads();

    // dense epilogue: out[b, m] = (pooled @ Wd[e])[m] * cell_mask[e, m]
    const float* wd = Wd + (size_t)e * 16 * MM;
    const float* cm = cmask + e * MM;
    #pragma unroll 1
    for (int m = tid; m < MM; m += 256) {
        float acc = 0.f;
        #pragma unroll
        for (int k = 0; k < 16; ++k) acc += pooledS[k] * wd[k * MM + m];
        out[(size_t)b * MM + m] = acc * cm[m];
    }
}

extern "C" void kernel_launch(void* const* d_in, const int* in_sizes, int n_in,
                              void* d_out, int out_size, void* d_ws, size_t ws_size,
                              hipStream_t stream) {
    const float* x    = (const float*)d_in[0];
    const int*   idx  = (const int*)  d_in[1];
    const float* W1   = (const float*)d_in[2];
    const float* W3   = (const float*)d_in[3];
    const float* Wsk  = (const float*)d_in[4];
    const float* Wd   = (const float*)d_in[5];
    const float* cmsk = (const float*)d_in[6];
    float* out = (float*)d_out;

    conv_moe_kernel<<<2048, 256, 0, stream>>>(x, idx, W1, W3, Wsk, Wd, cmsk, out);
}

// Round 2
// 340.726 us; speedup vs baseline: 7.6306x; 7.6306x over previous
//
#include <hip/hip_runtime.h>

#define HH 64
#define WW 64
#define MM 512

// One block per output row b in [0, 2048): e = b>>9, sample = idx[b].
// pooled[0:8]  = mean_hw relu(conv1x1(x, W1))
// pooled[8:16] = mean_hw relu(conv3x3(x, W3))
// pooled      += (mean_hw x) @ Wskip      (1x1 conv commutes with spatial mean)
// out[b,:]     = (pooled @ Wd[e]) * cell_mask[e]
__global__ __launch_bounds__(256, 4)
void conv_moe_kernel(const float* __restrict__ x,
                     const int*   __restrict__ idx,
                     const float* __restrict__ W1,
                     const float* __restrict__ W3,
                     const float* __restrict__ Wsk,
                     const float* __restrict__ Wd,
                     const float* __restrict__ cmask,
                     float*       __restrict__ out)
{
    // x tile: [channel-half][lds row 0..5][col 0..65], float4 each.
    // 16B/lane stride on reads -> conflict-free ds_read_b128. 12.7 KB.
    __shared__ float4 xs[2][6][66];
    __shared__ float red[4][24];
    __shared__ float rsum[24];
    __shared__ float pooledS[16];

    const int b    = blockIdx.x;
    const int e    = b >> 9;
    const int tid  = threadIdx.x;
    const int samp = idx[b];

    const float* xb = x + (size_t)samp * (HH * WW * 8);
    // wave-uniform weight pointers (blockIdx-derived) -> scalar loads
    const float* w3 = W3 + e * 576;   // [tap][cin][cout]
    const float* w1 = W1 + e * 64;    // [cin][cout]

    // zero the column halo once (cols 0 and 65 stay zero forever)
    const float4 z4 = make_float4(0.f, 0.f, 0.f, 0.f);
    if (tid < 12) {
        xs[tid & 1][tid >> 1][0] = z4;
    } else if (tid < 24) {
        const int t = tid - 12;
        xs[t & 1][t >> 1][65] = z4;
    }

    float s1[8], s3[8], sx[8];
    #pragma unroll
    for (int i = 0; i < 8; ++i) { s1[i] = 0.f; s3[i] = 0.f; sx[i] = 0.f; }

    const int prow = tid >> 6;   // 0..3 : my row within the 4-row strip
    const int col  = tid & 63;   // 0..63: my column

    #pragma unroll 1
    for (int iter = 0; iter < 16; ++iter) {
        const int r0 = iter * 4;

        __syncthreads();   // previous strip's reads done before overwrite
        // stage rows r0-1 .. r0+4 (zeros when out of range)
        #pragma unroll
        for (int j3 = 0; j3 < 3; ++j3) {
            const int j    = j3 * 256 + tid;  // 0..767
            const int half = j & 1;
            const int pl   = j >> 1;          // 0..383
            const int lrow = pl >> 6;         // 0..5
            const int c    = pl & 63;
            const int r    = r0 - 1 + lrow;
            float4 v = z4;
            if (r >= 0 && r < HH)
                v = *(const float4*)(xb + (((r << 6) + c) << 3) + (half << 2));
            xs[half][lrow][c + 1] = v;
        }
        __syncthreads();

        // ---- 3x3 branch ----
        float t3[8];
        #pragma unroll
        for (int c = 0; c < 8; ++c) t3[c] = 0.f;

        #pragma unroll
        for (int dr = 0; dr < 3; ++dr) {
            #pragma unroll
            for (int dc = 0; dc < 3; ++dc) {
                const float4 xa = xs[0][prow + dr][col + dc];
                const float4 xc = xs[1][prow + dr][col + dc];
                const float xv[8] = {xa.x, xa.y, xa.z, xa.w, xc.x, xc.y, xc.z, xc.w};
                const float* wt = w3 + (dr * 3 + dc) * 64;  // uniform -> SGPR
                #pragma unroll
                for (int ci = 0; ci < 8; ++ci)
                    #pragma unroll
                    for (int co = 0; co < 8; ++co)
                        t3[co] += xv[ci] * wt[ci * 8 + co];
            }
        }

        // ---- 1x1 branch + raw-input sum (center pixel) ----
        float t1[8];
        #pragma unroll
        for (int c = 0; c < 8; ++c) t1[c] = 0.f;
        {
            const float4 xa = xs[0][prow + 1][col + 1];
            const float4 xc = xs[1][prow + 1][col + 1];
            const float xv[8] = {xa.x, xa.y, xa.z, xa.w, xc.x, xc.y, xc.z, xc.w};
            #pragma unroll
            for (int ci = 0; ci < 8; ++ci) {
                sx[ci] += xv[ci];
                #pragma unroll
                for (int co = 0; co < 8; ++co)
                    t1[co] += xv[ci] * w1[ci * 8 + co];
            }
        }

        // relu + accumulate spatial sums
        #pragma unroll
        for (int c = 0; c < 8; ++c) {
            s3[c] += fmaxf(t3[c], 0.f);
            s1[c] += fmaxf(t1[c], 0.f);
        }
    }

    // ---- wave reduction (64 lanes) ----
    #pragma unroll
    for (int i = 0; i < 8; ++i) {
        #pragma unroll
        for (int off = 32; off > 0; off >>= 1) {
            s1[i] += __shfl_down(s1[i], off);
            s3[i] += __shfl_down(s3[i], off);
            sx[i] += __shfl_down(sx[i], off);
        }
    }
    const int lane = tid & 63;
    const int wid  = tid >> 6;
    if (lane == 0) {
        #pragma unroll
        for (int i = 0; i < 8; ++i) {
            red[wid][i]      = s1[i];
            red[wid][8 + i]  = s3[i];
            red[wid][16 + i] = sx[i];
        }
    }
    __syncthreads();
    if (tid < 24) {
        const float t = red[0][tid] + red[1][tid] + red[2][tid] + red[3][tid];
        rsum[tid] = t * (1.0f / 4096.0f);
    }
    __syncthreads();

    // pooled[k] = branch mean + (mean x) @ Wskip
    if (tid < 16) {
        float acc = rsum[tid];
        #pragma unroll
        for (int ci = 0; ci < 8; ++ci)
            acc += rsum[16 + ci] * Wsk[e * 128 + ci * 16 + tid];
        pooledS[tid] = acc;
    }
    __syncthreads();

    // dense epilogue
    const float* wd = Wd + (size_t)e * 16 * MM;
    const float* cm = cmask + e * MM;
    #pragma unroll 1
    for (int m = tid; m < MM; m += 256) {
        float acc = 0.f;
        #pragma unroll
        for (int k = 0; k < 16; ++k) acc += pooledS[k] * wd[k * MM + m];
        out[(size_t)b * MM + m] = acc * cm[m];
    }
}

extern "C" void kernel_launch(void* const* d_in, const int* in_sizes, int n_in,
                              void* d_out, int out_size, void* d_ws, size_t ws_size,
                              hipStream_t stream) {
    const float* x    = (const float*)d_in[0];
    const int*   idx  = (const int*)  d_in[1];
    const float* W1   = (const float*)d_in[2];
    const float* W3   = (const float*)d_in[3];
    const float* Wsk  = (const float*)d_in[4];
    const float* Wd   = (const float*)d_in[5];
    const float* cmsk = (const float*)d_in[6];
    float* out = (float*)d_out;

    conv_moe_kernel<<<2048, 256, 0, stream>>>(x, idx, W1, W3, Wsk, Wd, cmsk, out);
}

// Round 3
// 61.176 us; speedup vs baseline: 42.4995x; 5.5696x over previous
//
#include <hip/hip_runtime.h>
#include <hip/hip_bf16.h>

#define MM 512

typedef short bf16x8 __attribute__((ext_vector_type(8)));
typedef float f32x4  __attribute__((ext_vector_type(4)));

static __device__ inline short f2bf(float f) {
    __hip_bfloat16 h = __float2bfloat16(f);
    return *reinterpret_cast<short*>(&h);
}

// One block per output row b in [0,2048): e = b>>9, sample = idx[b].
// GEMM per 16-pixel tile: D[16px,16co] = A[16,96] @ B[96,16]
//   B cols 0-7  = W1 (center tap, k=32..39)
//   B cols 8-15 = W3 (taps 0..8, k=0..71; k>=72 zero)
// sx (skip-branch channel sums) via identity-B MFMA on the center-tap A frag.
// pooled = mean relu + (mean x)@Wskip ; out = (pooled@Wd)*mask
__global__ __launch_bounds__(256, 4)
void conv_moe_mfma(const float* __restrict__ x,
                   const int*   __restrict__ idx,
                   const float* __restrict__ W1,
                   const float* __restrict__ W3,
                   const float* __restrict__ Wsk,
                   const float* __restrict__ Wd,
                   const float* __restrict__ cmask,
                   float*       __restrict__ out)
{
    __shared__ short xbf[2][18][66][8];   // bf16 tile, col halo at 0 and 65
    __shared__ float red[4][16];
    __shared__ float redx[4][8];
    __shared__ float rsum[16];
    __shared__ float rsumx[8];
    __shared__ float pooledS[16];

    const int b    = blockIdx.x;
    const int e    = b >> 9;
    const int tid  = threadIdx.x;
    const int lane = tid & 63;
    const int wid  = tid >> 6;
    const int g    = lane >> 4;   // lane group 0..3
    const int p    = lane & 15;   // A: pixel row; B/D: cout column
    const int CB   = wid << 4;    // this wave's 16-col tile base

    const int samp = idx[b];
    const float* xb = x + (size_t)samp * 32768;

    // ---- B fragments (constant per block) ----
    const float* w3 = W3 + e * 576;  // [tap][cin][cout] (tap=kh*3+kw)
    const float* w1 = W1 + e * 64;   // [cin][cout]
    bf16x8 bf0, bf1, bf2, bid;
    #pragma unroll
    for (int j = 0; j < 8; ++j) {
        float v0 = 0.f, v1 = 0.f, v2 = 0.f, vi = 0.f;
        if (p >= 8) {                       // conv3 couts
            v0 = w3[g * 64 + j * 8 + (p - 8)];          // taps 0..3
            v1 = w3[(4 + g) * 64 + j * 8 + (p - 8)];    // taps 4..7
            if (g == 0) v2 = w3[8 * 64 + j * 8 + (p - 8)]; // tap 8
        } else {                            // conv1 couts (center tap = k 32..39)
            if (g == 0) { v1 = w1[j * 8 + p]; vi = (j == p) ? 1.f : 0.f; }
        }
        bf0[j] = f2bf(v0); bf1[j] = f2bf(v1); bf2[j] = f2bf(v2); bid[j] = f2bf(vi);
    }

    // ---- per-lane A read offsets (in shorts) ----
    // array col = image_col + 1; array row = rr - r0 + dr
    int off0, off1, off2;
    { const int t = g;     const int dr = t / 3, dc = t % 3; off0 = (dr * 66 + CB + p + dc) * 8; }
    { const int t = 4 + g; const int dr = t / 3, dc = t % 3; off1 = (dr * 66 + CB + p + dc) * 8; }
    {                      const int dr = 2,     dc = 2;     off2 = (dr * 66 + CB + p + dc) * 8; } // tap 8, bcast

    // ---- zero column halos of both buffers ----
    if (tid < 72) {
        const int bb = tid & 1, t = tid >> 1;     // t < 36
        const int rr = t % 18, side = t / 18;
        bf16x8 zv = {0,0,0,0,0,0,0,0};
        *(bf16x8*)&xbf[bb][rr][side ? 65 : 0][0] = zv;
    }

    // ---- staging: 18 rows (r0-1..r0+16) of 64 cols, fp32->bf16 ----
    #define STAGE(S, BB)                                                        \
    {                                                                           \
        const int r0s = (S) * 16;                                               \
        _Pragma("unroll")                                                       \
        for (int j5 = 0; j5 < 5; ++j5) {                                        \
            const int j = j5 * 256 + tid;                                       \
            if (j < 1152) {                                                     \
                const int lrow = j >> 6, c = j & 63;                            \
                const int r = r0s - 1 + lrow;                                   \
                bf16x8 v = {0,0,0,0,0,0,0,0};                                   \
                if (r >= 0 && r < 64) {                                         \
                    const float4* s4 = (const float4*)(xb + (((r << 6) + c) << 3)); \
                    const float4 aa = s4[0], bb4 = s4[1];                        \
                    v[0]=f2bf(aa.x); v[1]=f2bf(aa.y); v[2]=f2bf(aa.z); v[3]=f2bf(aa.w); \
                    v[4]=f2bf(bb4.x); v[5]=f2bf(bb4.y); v[6]=f2bf(bb4.z); v[7]=f2bf(bb4.w); \
                }                                                               \
                *(bf16x8*)&xbf[BB][lrow][c + 1][0] = v;                         \
            }                                                                   \
        }                                                                       \
    }

    f32x4 ssum = {0.f, 0.f, 0.f, 0.f};  // per-lane relu'd conv sums
    f32x4 acc2 = {0.f, 0.f, 0.f, 0.f};  // per-lane raw x sums (cols<8)

    STAGE(0, 0);
    __syncthreads();

    #pragma unroll 1
    for (int s = 0; s < 4; ++s) {
        if (s == 0) STAGE(1, 1);
        if (s == 1) STAGE(2, 0);
        if (s == 2) STAGE(3, 1);

        const short* base = &xbf[s & 1][0][0][0];
        #pragma unroll 2
        for (int rl = 0; rl < 16; ++rl) {
            const short* rbase = base + rl * (66 * 8);
            const bf16x8 a0 = *(const bf16x8*)(rbase + off0);
            const bf16x8 a1 = *(const bf16x8*)(rbase + off1);
            const bf16x8 a2 = *(const bf16x8*)(rbase + off2);
            f32x4 d = {0.f, 0.f, 0.f, 0.f};
            d = __builtin_amdgcn_mfma_f32_16x16x32_bf16(a0, bf0, d, 0, 0, 0);
            d = __builtin_amdgcn_mfma_f32_16x16x32_bf16(a1, bf1, d, 0, 0, 0);
            d = __builtin_amdgcn_mfma_f32_16x16x32_bf16(a2, bf2, d, 0, 0, 0);
            acc2 = __builtin_amdgcn_mfma_f32_16x16x32_bf16(a1, bid, acc2, 0, 0, 0);
            ssum[0] += fmaxf(d[0], 0.f);
            ssum[1] += fmaxf(d[1], 0.f);
            ssum[2] += fmaxf(d[2], 0.f);
            ssum[3] += fmaxf(d[3], 0.f);
        }
        __syncthreads();
    }

    // ---- reduce over pixels: sum regs, then across lane groups ----
    float scon = ssum[0] + ssum[1] + ssum[2] + ssum[3];
    float sxs  = acc2[0] + acc2[1] + acc2[2] + acc2[3];
    scon += __shfl_xor(scon, 16);
    scon += __shfl_xor(scon, 32);
    sxs  += __shfl_xor(sxs, 16);
    sxs  += __shfl_xor(sxs, 32);
    if (lane < 16) red[wid][lane]  = scon;
    if (lane < 8)  redx[wid][lane] = sxs;
    __syncthreads();
    if (tid < 16) rsum[tid]  = (red[0][tid] + red[1][tid] + red[2][tid] + red[3][tid]) * (1.f / 4096.f);
    if (tid < 8)  rsumx[tid] = (redx[0][tid] + redx[1][tid] + redx[2][tid] + redx[3][tid]) * (1.f / 4096.f);
    __syncthreads();

    if (tid < 16) {
        float acc = rsum[tid];   // cols 0-7: conv1 branch, 8-15: conv3 branch
        #pragma unroll
        for (int ci = 0; ci < 8; ++ci)
            acc += rsumx[ci] * Wsk[e * 128 + ci * 16 + tid];
        pooledS[tid] = acc;
    }
    __syncthreads();

    const float* wd = Wd + (size_t)e * 16 * MM;
    const float* cm = cmask + e * MM;
    #pragma unroll 1
    for (int m = tid; m < MM; m += 256) {
        float acc = 0.f;
        #pragma unroll
        for (int k = 0; k < 16; ++k) acc += pooledS[k] * wd[k * MM + m];
        out[(size_t)b * MM + m] = acc * cm[m];
    }
}

extern "C" void kernel_launch(void* const* d_in, const int* in_sizes, int n_in,
                              void* d_out, int out_size, void* d_ws, size_t ws_size,
                              hipStream_t stream) {
    const float* x    = (const float*)d_in[0];
    const int*   idx  = (const int*)  d_in[1];
    const float* W1   = (const float*)d_in[2];
    const float* W3   = (const float*)d_in[3];
    const float* Wsk  = (const float*)d_in[4];
    const float* Wd   = (const float*)d_in[5];
    const float* cmsk = (const float*)d_in[6];
    float* out = (float*)d_out;

    conv_moe_mfma<<<2048, 256, 0, stream>>>(x, idx, W1, W3, Wsk, Wd, cmsk, out);
}

// Round 4
// 52.292 us; speedup vs baseline: 49.7197x; 1.1699x over previous
//
#include <hip/hip_runtime.h>
#include <hip/hip_bf16.h>

#define MM 512

typedef short bf16x8 __attribute__((ext_vector_type(8)));
typedef float f32x4  __attribute__((ext_vector_type(4)));

static __device__ inline short f2bf(float f) {
    __hip_bfloat16 h = __float2bfloat16(f);
    return *reinterpret_cast<short*>(&h);
}

// One block per output row b in [0,2048): e = b>>9, sample = idx[b].
// GEMM per 16-pixel tile: D[16px,16co] = A[16,96] @ B[96,16]
//   B cols 0-7  = W1 (center tap, k=32..39)
//   B cols 8-15 = W3 (taps 0..8, k=0..71; k>=72 zero)
// sx (skip-branch channel sums) via identity-B MFMA on the center-tap A frag.
// pooled = mean relu + (mean x)@Wskip ; out = (pooled@Wd)*mask
//
// T14 async staging: global loads for strip s+1 are issued (into regs)
// right after the LDS-visibility barrier, so HBM latency hides under the
// MFMA/ds_read compute of strip s. cvt+ds_write happen next iteration.
// Single 19 KB LDS buffer (in-flight strip lives in regs, not LDS).
__global__ __launch_bounds__(256, 4)
void conv_moe_mfma(const float* __restrict__ x,
                   const int*   __restrict__ idx,
                   const float* __restrict__ W1,
                   const float* __restrict__ W3,
                   const float* __restrict__ Wsk,
                   const float* __restrict__ Wd,
                   const float* __restrict__ cmask,
                   float*       __restrict__ out)
{
    __shared__ short xbf[18][66][8];   // bf16 strip, col halo at 0 and 65 (19 KB)
    __shared__ float red[4][16];
    __shared__ float redx[4][8];
    __shared__ float rsum[16];
    __shared__ float rsumx[8];
    __shared__ float pooledS[16];

    const int b    = blockIdx.x;
    const int e    = b >> 9;
    const int tid  = threadIdx.x;
    const int lane = tid & 63;
    const int wid  = tid >> 6;
    const int g    = lane >> 4;   // lane group 0..3
    const int p    = lane & 15;   // A: pixel row; B/D: cout column
    const int CB   = wid << 4;    // this wave's 16-col tile base

    const int samp = idx[b];
    const float* xb = x + (size_t)samp * 32768;

    // ---- B fragments (constant per block) ----
    const float* w3 = W3 + e * 576;  // [tap][cin][cout] (tap=kh*3+kw)
    const float* w1 = W1 + e * 64;   // [cin][cout]
    bf16x8 bf0, bf1, bf2, bid;
    #pragma unroll
    for (int j = 0; j < 8; ++j) {
        float v0 = 0.f, v1 = 0.f, v2 = 0.f, vi = 0.f;
        if (p >= 8) {                       // conv3 couts
            v0 = w3[g * 64 + j * 8 + (p - 8)];             // taps 0..3
            v1 = w3[(4 + g) * 64 + j * 8 + (p - 8)];       // taps 4..7
            if (g == 0) v2 = w3[8 * 64 + j * 8 + (p - 8)]; // tap 8
        } else {                            // conv1 couts (center tap = k 32..39)
            if (g == 0) { v1 = w1[j * 8 + p]; vi = (j == p) ? 1.f : 0.f; }
        }
        bf0[j] = f2bf(v0); bf1[j] = f2bf(v1); bf2[j] = f2bf(v2); bid[j] = f2bf(vi);
    }

    // ---- per-lane A read offsets (in shorts) ----
    int off0, off1, off2;
    { const int t = g;     const int dr = t / 3, dc = t % 3; off0 = (dr * 66 + CB + p + dc) * 8; }
    { const int t = 4 + g; const int dr = t / 3, dc = t % 3; off1 = (dr * 66 + CB + p + dc) * 8; }
    {                      const int dr = 2,     dc = 2;     off2 = (dr * 66 + CB + p + dc) * 8; }

    // ---- zero column halos once (cols 0 and 65 stay zero) ----
    if (tid < 36) {
        const int rr = tid % 18, side = tid / 18;
        bf16x8 zv = {0,0,0,0,0,0,0,0};
        *(bf16x8*)&xbf[rr][side ? 65 : 0][0] = zv;
    }

    const float4 z4 = make_float4(0.f, 0.f, 0.f, 0.f);
    float4 ra[5][2];   // in-flight strip: up to 5 pixels x 32B per thread

    // issue global loads for strip S into regs (no wait here)
    #define STAGE_LOAD(S)                                                       \
    {                                                                           \
        const int r0s = (S) * 16;                                               \
        _Pragma("unroll")                                                       \
        for (int j5 = 0; j5 < 5; ++j5) {                                        \
            const int j = j5 * 256 + tid;                                       \
            ra[j5][0] = z4; ra[j5][1] = z4;                                     \
            if (j < 1152) {                                                     \
                const int lrow = j >> 6, c = j & 63;                            \
                const int r = r0s - 1 + lrow;                                   \
                if (r >= 0 && r < 64) {                                         \
                    const float4* s4 = (const float4*)(xb + (((r << 6) + c) << 3)); \
                    ra[j5][0] = s4[0];                                          \
                    ra[j5][1] = s4[1];                                          \
                }                                                               \
            }                                                                   \
        }                                                                       \
    }

    // cvt + LDS write of the strip currently held in regs
    #define STAGE_WRITE()                                                       \
    {                                                                           \
        _Pragma("unroll")                                                       \
        for (int j5 = 0; j5 < 5; ++j5) {                                        \
            const int j = j5 * 256 + tid;                                       \
            if (j < 1152) {                                                     \
                const int lrow = j >> 6, c = j & 63;                            \
                bf16x8 v;                                                       \
                v[0] = f2bf(ra[j5][0].x); v[1] = f2bf(ra[j5][0].y);             \
                v[2] = f2bf(ra[j5][0].z); v[3] = f2bf(ra[j5][0].w);             \
                v[4] = f2bf(ra[j5][1].x); v[5] = f2bf(ra[j5][1].y);             \
                v[6] = f2bf(ra[j5][1].z); v[7] = f2bf(ra[j5][1].w);             \
                *(bf16x8*)&xbf[lrow][c + 1][0] = v;                             \
            }                                                                   \
        }                                                                       \
    }

    f32x4 ssum = {0.f, 0.f, 0.f, 0.f};  // per-lane relu'd conv sums
    f32x4 acc2 = {0.f, 0.f, 0.f, 0.f};  // per-lane raw x sums (cols<8)

    STAGE_LOAD(0);

    #pragma unroll 1
    for (int s = 0; s < 4; ++s) {
        STAGE_WRITE();                 // waits vmcnt for its own data only
        __syncthreads();               // strip visible to all waves
        if (s < 3) STAGE_LOAD(s + 1);  // async: latency hides under compute

        const short* base = &xbf[0][0][0];
        #pragma unroll 2
        for (int rl = 0; rl < 16; ++rl) {
            const short* rbase = base + rl * (66 * 8);
            const bf16x8 a0 = *(const bf16x8*)(rbase + off0);
            const bf16x8 a1 = *(const bf16x8*)(rbase + off1);
            const bf16x8 a2 = *(const bf16x8*)(rbase + off2);
            f32x4 d = {0.f, 0.f, 0.f, 0.f};
            d = __builtin_amdgcn_mfma_f32_16x16x32_bf16(a0, bf0, d, 0, 0, 0);
            d = __builtin_amdgcn_mfma_f32_16x16x32_bf16(a1, bf1, d, 0, 0, 0);
            d = __builtin_amdgcn_mfma_f32_16x16x32_bf16(a2, bf2, d, 0, 0, 0);
            acc2 = __builtin_amdgcn_mfma_f32_16x16x32_bf16(a1, bid, acc2, 0, 0, 0);
            ssum[0] += fmaxf(d[0], 0.f);
            ssum[1] += fmaxf(d[1], 0.f);
            ssum[2] += fmaxf(d[2], 0.f);
            ssum[3] += fmaxf(d[3], 0.f);
        }
        __syncthreads();               // all reads done before next overwrite
    }

    // ---- reduce over pixels: sum regs, then across lane groups ----
    float scon = ssum[0] + ssum[1] + ssum[2] + ssum[3];
    float sxs  = acc2[0] + acc2[1] + acc2[2] + acc2[3];
    scon += __shfl_xor(scon, 16);
    scon += __shfl_xor(scon, 32);
    sxs  += __shfl_xor(sxs, 16);
    sxs  += __shfl_xor(sxs, 32);
    if (lane < 16) red[wid][lane]  = scon;
    if (lane < 8)  redx[wid][lane] = sxs;
    __syncthreads();
    if (tid < 16) rsum[tid]  = (red[0][tid] + red[1][tid] + red[2][tid] + red[3][tid]) * (1.f / 4096.f);
    if (tid < 8)  rsumx[tid] = (redx[0][tid] + redx[1][tid] + redx[2][tid] + redx[3][tid]) * (1.f / 4096.f);
    __syncthreads();

    if (tid < 16) {
        float acc = rsum[tid];   // cols 0-7: conv1 branch, 8-15: conv3 branch
        #pragma unroll
        for (int ci = 0; ci < 8; ++ci)
            acc += rsumx[ci] * Wsk[e * 128 + ci * 16 + tid];
        pooledS[tid] = acc;
    }
    __syncthreads();

    const float* wd = Wd + (size_t)e * 16 * MM;
    const float* cm = cmask + e * MM;
    #pragma unroll 1
    for (int m = tid; m < MM; m += 256) {
        float acc = 0.f;
        #pragma unroll
        for (int k = 0; k < 16; ++k) acc += pooledS[k] * wd[k * MM + m];
        out[(size_t)b * MM + m] = acc * cm[m];
    }
}

extern "C" void kernel_launch(void* const* d_in, const int* in_sizes, int n_in,
                              void* d_out, int out_size, void* d_ws, size_t ws_size,
                              hipStream_t stream) {
    const float* x    = (const float*)d_in[0];
    const int*   idx  = (const int*)  d_in[1];
    const float* W1   = (const float*)d_in[2];
    const float* W3   = (const float*)d_in[3];
    const float* Wsk  = (const float*)d_in[4];
    const float* Wd   = (const float*)d_in[5];
    const float* cmsk = (const float*)d_in[6];
    float* out = (float*)d_out;

    conv_moe_mfma<<<2048, 256, 0, stream>>>(x, idx, W1, W3, Wsk, Wd, cmsk, out);
}